// Round 8
// baseline (92.227 us; speedup 1.0000x reference)
//
#include <hip/hip_runtime.h>
#include <hip/hip_bf16.h>
#include <cmath>

// B=128, T=256, D=1024, V=32000, E=300
// d_out (floats): logits[0..4096000), h_new[4096000), c_new[4227072),
//                 attn[4358144), context[4390912), total 4521984

#define Bc 128
#define Tc 256
#define Dc 1024
#define Vc 32000
#define Ec 300
#define KREAL 2348        // D + E + D
#define KXP 2688          // padded: 7 splits x 6 steps x 64
#define KSPLIT 7
#define N4 4096

typedef __attribute__((ext_vector_type(8))) short bf16x8;
typedef __attribute__((ext_vector_type(4))) float f32x4;

static __device__ __forceinline__ short f2bf(float x) {
    __hip_bfloat16 b = __float2bfloat16(x);   // RNE
    return *reinterpret_cast<short*>(&b);
}
static __device__ __forceinline__ unsigned pack2(float a, float b) {
    return (unsigned)(unsigned short)f2bf(a) | ((unsigned)(unsigned short)f2bf(b) << 16);
}

// ---- A (fused attention): one block per b. 128 blocks x 1024 threads.
// Wave w handles rows t = 16w..16w+15: score (64-lane dot + butterfly) and
// in-register ctx partial. Cross-wave reduce, softmax, x_bf16 pack in LDS.
__global__ __launch_bounds__(1024) void k_att(
        const float* __restrict__ enc, const float* __restrict__ h,
        const int* __restrict__ idx, const float* __restrict__ emb_table,
        float* __restrict__ ctx_out, float* __restrict__ attn_out,
        unsigned short* __restrict__ x_bf) {
    const int b = blockIdx.x;
    const int tid = threadIdx.x;
    const int wave = tid >> 6, lane = tid & 63;
    __shared__ float s_acc[16][1024];   // 64 KB wave-partial ctx
    __shared__ float s_sc[256];
    __shared__ float red[256];

    const float4* h4 = (const float4*)(h + ((size_t)b << 10));
    float4 hv0 = h4[lane], hv1 = h4[lane + 64], hv2 = h4[lane + 128], hv3 = h4[lane + 192];

    float4 a0 = {0,0,0,0}, a1 = {0,0,0,0}, a2 = {0,0,0,0}, a3 = {0,0,0,0};
    const int t0 = wave << 4;
    const float4* e4 = (const float4*)(enc + ((size_t)(b * Tc + t0) << 10));

    #pragma unroll 2
    for (int i = 0; i < 16; ++i) {
        float4 e0 = e4[lane], e1 = e4[lane + 64], e2 = e4[lane + 128], e3 = e4[lane + 192];
        e4 += 256;
        float d = e0.x*hv0.x + e0.y*hv0.y + e0.z*hv0.z + e0.w*hv0.w
                + e1.x*hv1.x + e1.y*hv1.y + e1.z*hv1.z + e1.w*hv1.w
                + e2.x*hv2.x + e2.y*hv2.y + e2.z*hv2.z + e2.w*hv2.w
                + e3.x*hv3.x + e3.y*hv3.y + e3.z*hv3.z + e3.w*hv3.w;
        #pragma unroll
        for (int off = 32; off; off >>= 1) d += __shfl_xor(d, off, 64);
        if (lane == 0) s_sc[t0 + i] = d;
        a0.x += d*e0.x; a0.y += d*e0.y; a0.z += d*e0.z; a0.w += d*e0.w;
        a1.x += d*e1.x; a1.y += d*e1.y; a1.z += d*e1.z; a1.w += d*e1.w;
        a2.x += d*e2.x; a2.y += d*e2.y; a2.z += d*e2.z; a2.w += d*e2.w;
        a3.x += d*e3.x; a3.y += d*e3.y; a3.z += d*e3.z; a3.w += d*e3.w;
    }
    *(float4*)&s_acc[wave][lane << 2]         = a0;
    *(float4*)&s_acc[wave][256 + (lane << 2)] = a1;
    *(float4*)&s_acc[wave][512 + (lane << 2)] = a2;
    *(float4*)&s_acc[wave][768 + (lane << 2)] = a3;
    __syncthreads();

    // cross-wave reduce: thread owns column tid
    float cv = 0.f;
    #pragma unroll
    for (int w = 0; w < 16; ++w) cv += s_acc[w][tid];
    ctx_out[((size_t)b << 10) + tid] = cv;
    s_acc[0][tid] = cv;                 // only col tid touched; safe
    __syncthreads();

    unsigned short* xb = x_bf + (size_t)b * KXP;
    if (tid < 512) {
        // ctx pack (pairs)
        *(unsigned*)&xb[tid << 1] = pack2(s_acc[0][tid << 1], s_acc[0][(tid << 1) + 1]);
        // h pack (pairs)
        float2 hp = *(const float2*)(h + ((size_t)b << 10) + (tid << 1));
        *(unsigned*)&xb[(Dc + Ec) + (tid << 1)] = pack2(hp.x, hp.y);
    } else if (tid < 812) {
        int i = tid - 512;              // emb pack
        int row = idx[b];
        xb[Dc + i] = (unsigned short)f2bf(emb_table[(size_t)row * Ec + i]);
    } else if (tid < 812 + (KXP - KREAL)) {
        xb[KREAL + (tid - 812)] = 0;    // zero pad
    }

    // softmax over 256 scores (all threads hit barriers)
    float v = (tid < 256) ? s_sc[tid] : -1e30f;
    if (tid < 256) red[tid] = v;
    __syncthreads();
    for (int s = 128; s; s >>= 1) {
        if (tid < s) red[tid] = fmaxf(red[tid], red[tid + s]);
        __syncthreads();
    }
    float m = red[0];
    __syncthreads();
    float e = __expf(v - m);
    if (tid < 256) red[tid] = e;
    __syncthreads();
    for (int s = 128; s; s >>= 1) {
        if (tid < s) red[tid] += red[tid + s];
        __syncthreads();
    }
    if (tid < 256) attn_out[(b << 8) + tid] = e / red[0];
}

// ---- Z: z partials, bf16 MFMA, LDS dbuf + early-issue. grid (64,7) x 512 ----
__global__ __launch_bounds__(512) void k_zgemm_mfma(
        const unsigned short* __restrict__ xbf, const float* __restrict__ Wl,
        const float* __restrict__ Ul, float* __restrict__ z_part) {
    __shared__ __align__(16) short blds[2 * 8 * 64 * 8];   // 16 KB
    const int tid  = threadIdx.x;
    const int wid  = tid >> 6;
    const int lane = tid & 63;
    const int g    = lane >> 4;
    const int r    = lane & 15;
    const int n0   = blockIdx.x << 6;     // 64-wide n tile
    const int ksp  = blockIdx.y;          // 0..6, steps ksp*6 .. ksp*6+5

    const int pr = tid >> 4;
    const int c  = tid & 15;
    const int kk = (pr << 1) & 31;
    const int gg = kk >> 3, jj = kk & 7;
    const int ks0 = pr >> 4;              // 0 or 1

    f32x4 acc[4] = {};
    const unsigned short* xrow = xbf + (size_t)((wid << 4) + r) * KXP;

    float4 wra[2], wrb[2];
    bf16x8 areg[2][2];

    auto loadWU = [&](int gk) -> float4 {
        if (gk < 1324) return *(const float4*)(Wl + (size_t)gk * N4 + n0 + (c << 2));
        if (gk < KREAL) return *(const float4*)(Ul + (size_t)(gk - 1324) * N4 + n0 + (c << 2));
        return float4{0.f, 0.f, 0.f, 0.f};
    };

    {
        const int kt = (ksp * 6) << 6;
        wra[0] = loadWU(kt + (pr << 1));
        wrb[0] = loadWU(kt + (pr << 1) + 1);
        areg[0][0] = *(const bf16x8*)&xrow[kt + (g << 3)];
        areg[0][1] = *(const bf16x8*)&xrow[kt + 32 + (g << 3)];
    }

    #pragma unroll
    for (int t = 0; t < 6; ++t) {
        const int cur = t & 1;
        const int coff = cur << 12;       // shorts
        {
            const float av[4] = {wra[cur].x, wra[cur].y, wra[cur].z, wra[cur].w};
            const float bv[4] = {wrb[cur].x, wrb[cur].y, wrb[cur].z, wrb[cur].w};
            #pragma unroll
            for (int i = 0; i < 4; ++i) {
                int n = (c << 2) + i;
                int nt = n >> 4;
                int inner = (gg << 4) | (n & 15);
                int Xs = ((((ks0 << 2) + nt) << 6) | inner) ^ nt;
                *(unsigned*)&blds[coff + (Xs << 3) + jj] = pack2(av[i], bv[i]);
            }
        }
        if (t < 5) {
            const int kt = ((ksp * 6) + t + 1) << 6;
            wra[cur ^ 1] = loadWU(kt + (pr << 1));
            wrb[cur ^ 1] = loadWU(kt + (pr << 1) + 1);
            areg[cur ^ 1][0] = *(const bf16x8*)&xrow[kt + (g << 3)];
            areg[cur ^ 1][1] = *(const bf16x8*)&xrow[kt + 32 + (g << 3)];
        }
        __syncthreads();
        #pragma unroll
        for (int ks = 0; ks < 2; ++ks) {
            #pragma unroll
            for (int nt = 0; nt < 4; ++nt) {
                int Xs = ((((ks << 2) + nt) << 6) | lane) ^ nt;
                bf16x8 bfr = *(const bf16x8*)&blds[coff + (Xs << 3)];
                acc[nt] = __builtin_amdgcn_mfma_f32_16x16x32_bf16(areg[cur][ks], bfr, acc[nt], 0, 0, 0);
            }
        }
    }

    float* zp = z_part + ((size_t)ksp << 19);
    #pragma unroll
    for (int nt = 0; nt < 4; ++nt) {
        int col = n0 + (nt << 4) + r;
        #pragma unroll
        for (int j = 0; j < 4; ++j) {
            int rowm = (wid << 4) + (g << 2) + j;
            zp[((size_t)rowm << 12) + col] = acc[nt][j];
        }
    }
}

// ---- G: sum 7 partials + bias -> gates -> c_new, h_new, h_bf16 (float4) ----
__global__ void k_gates(const float* __restrict__ z_part, const float* __restrict__ b_lstm,
                        const float* __restrict__ c_in, float* __restrict__ h_new,
                        float* __restrict__ c_new, unsigned short* __restrict__ h_bf) {
    int i = blockIdx.x * 256 + threadIdx.x;    // < 32768 (each handles 4 d)
    int b = i >> 8, d4 = (i & 255) << 2;
    size_t base = ((size_t)b << 12) + d4;
    float4 zi = *(const float4*)(b_lstm + d4);
    float4 zf = *(const float4*)(b_lstm + d4 + 1024);
    float4 zg = *(const float4*)(b_lstm + d4 + 2048);
    float4 zo = *(const float4*)(b_lstm + d4 + 3072);
    #pragma unroll
    for (int ks = 0; ks < KSPLIT; ++ks) {
        const float* zp = z_part + ((size_t)ks << 19);
        float4 t;
        t = *(const float4*)(zp + base);        zi.x += t.x; zi.y += t.y; zi.z += t.z; zi.w += t.w;
        t = *(const float4*)(zp + base + 1024); zf.x += t.x; zf.y += t.y; zf.z += t.z; zf.w += t.w;
        t = *(const float4*)(zp + base + 2048); zg.x += t.x; zg.y += t.y; zg.z += t.z; zg.w += t.w;
        t = *(const float4*)(zp + base + 3072); zo.x += t.x; zo.y += t.y; zo.z += t.z; zo.w += t.w;
    }
    float4 cin = *(const float4*)(c_in + ((size_t)b << 10) + d4);
    float4 cn, hn;
    {
        float si = 1.f/(1.f+__expf(-zi.x)), sf = 1.f/(1.f+__expf(-zf.x)), so = 1.f/(1.f+__expf(-zo.x));
        cn.x = sf*cin.x + si*tanhf(zg.x); hn.x = so*tanhf(cn.x);
        si = 1.f/(1.f+__expf(-zi.y)); sf = 1.f/(1.f+__expf(-zf.y)); so = 1.f/(1.f+__expf(-zo.y));
        cn.y = sf*cin.y + si*tanhf(zg.y); hn.y = so*tanhf(cn.y);
        si = 1.f/(1.f+__expf(-zi.z)); sf = 1.f/(1.f+__expf(-zf.z)); so = 1.f/(1.f+__expf(-zo.z));
        cn.z = sf*cin.z + si*tanhf(zg.z); hn.z = so*tanhf(cn.z);
        si = 1.f/(1.f+__expf(-zi.w)); sf = 1.f/(1.f+__expf(-zf.w)); so = 1.f/(1.f+__expf(-zo.w));
        cn.w = sf*cin.w + si*tanhf(zg.w); hn.w = so*tanhf(cn.w);
    }
    *(float4*)(c_new + ((size_t)b << 10) + d4) = cn;
    *(float4*)(h_new + ((size_t)b << 10) + d4) = hn;
    uint2 hp; hp.x = pack2(hn.x, hn.y); hp.y = pack2(hn.z, hn.w);
    *(uint2*)&h_bf[((size_t)b << 10) + d4] = hp;
}

// ---- L: logits, bf16 MFMA, K-step 128, LDS dbuf + early-issue. 500 x 512 ----
__global__ __launch_bounds__(512) void k_logits_mfma(
        const unsigned short* __restrict__ hbf, const float* __restrict__ Wd,
        const float* __restrict__ bd, float* __restrict__ out) {
    __shared__ __align__(16) short blds[2 * 16 * 64 * 8];   // 32 KB
    const int tid  = threadIdx.x;
    const int wid  = tid >> 6;
    const int lane = tid & 63;
    const int g    = lane >> 4;
    const int r    = lane & 15;
    const int n0   = blockIdx.x << 6;     // 64-wide n tile

    const int pr = tid >> 4;              // 0..31
    const int c  = tid & 15;
    const int kk = (pr << 1) & 31;
    const int gg = kk >> 3, jj = kk & 7;
    const int ksA = pr >> 4;              // task0: 0..1
    const int ksB = ksA + 2;              // task1: 2..3

    f32x4 acc[4] = {};
    const unsigned short* hrow = hbf + ((size_t)((wid << 4) + r) << 10);
    const float* wbase = Wd + (size_t)(pr << 1) * Vc + n0 + (c << 2);

    float4 wra[2], wrb[2], wrc[2], wrd[2];
    bf16x8 areg[2][4];

    {
        wra[0] = *(const float4*)(wbase);
        wrb[0] = *(const float4*)(wbase + Vc);
        wrc[0] = *(const float4*)(wbase + (size_t)64 * Vc);
        wrd[0] = *(const float4*)(wbase + (size_t)65 * Vc);
        #pragma unroll
        for (int ks = 0; ks < 4; ++ks)
            areg[0][ks] = *(const bf16x8*)&hrow[(ks << 5) + (g << 3)];
    }

    #pragma unroll
    for (int t = 0; t < 8; ++t) {
        const int cur = t & 1;
        const int coff = cur << 13;       // shorts
        {
            const float a0[4] = {wra[cur].x, wra[cur].y, wra[cur].z, wra[cur].w};
            const float b0[4] = {wrb[cur].x, wrb[cur].y, wrb[cur].z, wrb[cur].w};
            const float c0[4] = {wrc[cur].x, wrc[cur].y, wrc[cur].z, wrc[cur].w};
            const float d0[4] = {wrd[cur].x, wrd[cur].y, wrd[cur].z, wrd[cur].w};
            #pragma unroll
            for (int i = 0; i < 4; ++i) {
                int n = (c << 2) + i;
                int nt = n >> 4;
                int inner = (gg << 4) | (n & 15);
                int XsA = ((((ksA << 2) + nt) << 6) | inner) ^ nt;
                int XsB = ((((ksB << 2) + nt) << 6) | inner) ^ nt;
                *(unsigned*)&blds[coff + (XsA << 3) + jj] = pack2(a0[i], b0[i]);
                *(unsigned*)&blds[coff + (XsB << 3) + jj] = pack2(c0[i], d0[i]);
            }
        }
        if (t < 7) {
            const float* wb2 = wbase + (size_t)((t + 1) << 7) * Vc;
            wra[cur ^ 1] = *(const float4*)(wb2);
            wrb[cur ^ 1] = *(const float4*)(wb2 + Vc);
            wrc[cur ^ 1] = *(const float4*)(wb2 + (size_t)64 * Vc);
            wrd[cur ^ 1] = *(const float4*)(wb2 + (size_t)65 * Vc);
            #pragma unroll
            for (int ks = 0; ks < 4; ++ks)
                areg[cur ^ 1][ks] = *(const bf16x8*)&hrow[((t + 1) << 7) + (ks << 5) + (g << 3)];
        }
        __syncthreads();
        #pragma unroll
        for (int ks = 0; ks < 4; ++ks) {
            #pragma unroll
            for (int nt = 0; nt < 4; ++nt) {
                int Xs = ((((ks << 2) + nt) << 6) | lane) ^ nt;
                bf16x8 bfr = *(const bf16x8*)&blds[coff + (Xs << 3)];
                acc[nt] = __builtin_amdgcn_mfma_f32_16x16x32_bf16(areg[cur][ks], bfr, acc[nt], 0, 0, 0);
            }
        }
    }

    #pragma unroll
    for (int nt = 0; nt < 4; ++nt) {
        int col = n0 + (nt << 4) + r;
        float bias = bd[col];
        #pragma unroll
        for (int j = 0; j < 4; ++j) {
            int row = (wid << 4) + (g << 2) + j;
            out[(size_t)row * Vc + col] = acc[nt][j] + bias;
        }
    }
}

extern "C" void kernel_launch(void* const* d_in, const int* in_sizes, int n_in,
                              void* d_out, int out_size, void* d_ws, size_t ws_size,
                              hipStream_t stream) {
    const int*   idx = (const int*)d_in[0];
    const float* enc = (const float*)d_in[1];
    const float* h   = (const float*)d_in[2];
    const float* c   = (const float*)d_in[3];
    const float* emb = (const float*)d_in[4];
    const float* Wl  = (const float*)d_in[5];
    const float* Ul  = (const float*)d_in[6];
    const float* bl  = (const float*)d_in[7];
    const float* Wd  = (const float*)d_in[8];
    const float* bd  = (const float*)d_in[9];

    float* out    = (float*)d_out;
    float* logits = out;                 // 4,096,000
    float* h_new  = out + 4096000;
    float* c_new  = out + 4227072;
    float* attn   = out + 4358144;
    float* ctx    = out + 4390912;

    // z_part (zgemm->gates, consumed before logits) lives in the logits region.
    // x_bf16 (att->zgemm) and h_bf16 (gates->logits) live in d_ws — logits
    // writes [0,4096000) so nothing it (or zgemm) READS may alias that span.
    float*          z_part = out;                             // 7*524,288 = 3,670,016
    unsigned short* x_bf16 = (unsigned short*)d_ws;           // 344,064 shorts
    unsigned short* h_bf16 = (unsigned short*)d_ws + 344064;  // 131,072 shorts

    hipLaunchKernelGGL(k_att, dim3(128), dim3(1024), 0, stream, enc, h, idx, emb, ctx, attn, x_bf16);
    hipLaunchKernelGGL(k_zgemm_mfma, dim3(64, KSPLIT), dim3(512), 0, stream, x_bf16, Wl, Ul, z_part);
    hipLaunchKernelGGL(k_gates, dim3(128), dim3(256), 0, stream, z_part, bl, c, h_new, c_new, h_bf16);
    hipLaunchKernelGGL(k_logits_mfma, dim3(500), dim3(512), 0, stream, h_bf16, Wd, bd, logits);
}